// Round 6
// baseline (129.043 us; speedup 1.0000x reference)
//
#include <hip/hip_runtime.h>
#include <math.h>

// GEBLNet via Gram-matrix reduction.
// R23 = LDS-INSTRUCTION diet. EVIDENCE: R21 (VMEM 286->104, flat) and R22
// (2 pts/wave, VMEM+index halved, regressed via residency) falsified VMEM
// and index-math as binders; FMA count never changed. Remaining pipe that
// fits the ~5400 CU-cycle/point invariant: LDS. R19 structure issues ~560
// wave DS-instrs/point (2a: 286r+22w, 2b: 156r, ph4-6: ~100) ~ 3400 cy/pt
// ~ 60%+ LDS-pipe busy at 32 pts/CU. This round cuts DS instrs ~560 -> ~240:
//   (a) 2a inverted: lane=(rgrp 0..6, jk 0..8); We column (13 float2) loaded
//       to REGISTERS once per point from transposed WeT[ik][v] (b128 runs).
//       Row sweep loads only w1 (global, L1-hot). 2a DS reads 286 -> 7.
//   (b) B stored transposed [uu][jk][v], rows padded to 14 float2 so 2b
//       reads We-col and B-col as contiguous 16B-aligned runs: 156 -> ~84.
//   (c) Hs rows padded to 10 (16B-aligned) for b128 phase-4 reads: 54 -> ~30.
//   LDS total 1008 + 6048 + 960 = 8016 -> 8192 alloc (unchanged).
// LESSON (R22): 2 pts/wave regresses (residency halves). LESSON (R21): VMEM
// cut alone flat. LESSON (R20): multi-wave wgs regress. LESSON (R19): ILP
// unroll works; VGPR<=84 tolerable. LESSON (R18): broadcast reads conflict-
// free. LESSON (R16): merged 2a+2b VGPR 84 regress. LESSON (R15): fine-
// grained jobs. LESSON (R11): direct-w2 regresses. LESSON (R4+R7):
// launch_bounds min-waves arg -> spill. LESSON (R6): unions, never
// reinterpret-cast local arrays.

#define NPTS 8192
#define THRESH 0.001f

__global__ void geblnet_setup(const float* __restrict__ w2,
                              float4* __restrict__ CTt) {
    int j = blockIdx.x * blockDim.x + threadIdx.x;
    if (j >= 12 * 169) return;
    int u = j / 169, it = j % 169;
    const float* W = w2 + u * 25 * 25 * 2;
#define WR(v, w) W[((v) * 25 + (w)) * 2]
#define WI(v, w) W[((v) * 25 + (w)) * 2 + 1]
    float c0, c1, c2, c3;
    if (it < 78) {                       // S pairs, a<=b
        int q = it, a = 0;
        while (q >= 12 - a) { q -= 12 - a; ++a; }
        int b = a + q;
        float ar = WR(a, b) + (a != b ? WR(b, a) : 0.f);
        float ai = WI(a, b) + (a != b ? WI(b, a) : 0.f);
        float br = WR(12 + a, 12 + b) + (a != b ? WR(12 + b, 12 + a) : 0.f);
        float bi = WI(12 + a, 12 + b) + (a != b ? WI(12 + b, 12 + a) : 0.f);
        c0 = ar + br; c1 = bi - ai; c2 = ai + bi; c3 = ar - br;
    } else if (it < 156) {               // Hm pairs, a<=b
        int q = it - 78, a = 0;
        while (q >= 12 - a) { q -= 12 - a; ++a; }
        int b = a + q;
        if (a != b) {
            float gr = WR(a, 12 + b) + WR(12 + b, a);
            float gi = WI(a, 12 + b) + WI(12 + b, a);
            float dr = WR(b, 12 + a) + WR(12 + a, b);
            float di = WI(b, 12 + a) + WI(12 + a, b);
            c0 = gr + dr; c1 = di - gi; c2 = gi + di; c3 = gr - dr;
        } else {
            float er = WR(a, 12 + a) + WR(12 + a, a);
            float ei = WI(a, 12 + a) + WI(12 + a, a);
            c0 = er; c1 = 0.f; c2 = ei; c3 = 0.f;
        }
    } else if (it < 168) {               // trace terms
        int a = it - 156;
        float fr = WR(a, 24) + WR(24, a), fi = WI(a, 24) + WI(24, a);
        float pr = WR(12 + a, 24) + WR(24, 12 + a);
        float pi = WI(12 + a, 24) + WI(24, 12 + a);
        c0 = fr + pr; c1 = pi - fi; c2 = fi + pi; c3 = fr - pr;
    } else {                             // unit-unit
        c0 = 3.f * WR(24, 24); c1 = 0.f; c2 = 3.f * WI(24, 24); c3 = 0.f;
    }
    CTt[it * 12 + u] = make_float4(c0, c1, c2, c3);
#undef WR
#undef WI
}

// Overlays (unions; no reinterpret-cast of LDS per LESSON R6):
//   WeTU: WeT[ik][v] (rows pad 14, 16B-aligned) lives through phase 2b;
//         phase-3..6 scratch (tpar/tr1/sc1) overlays after.
//   BsU:  B[uu][jk][v] (rows pad 14) lives through 2b; GV[169] overlays.
union WeTU {
    float2 weT[9 * 14];                 // 1008 B
    struct {
        float2 tpar[60];                // 480 B, phase-5 partials
        float2 tr1[12];                 // 96 B, layer-1 traces
        float  sc1[12];                 // 48 B, gerelu+trnorm scale
    } s;
};
union BsU {
    float2 bs[6 * 9 * 14];              // 6048 B
    float2 gv[169];                     // 1352 B
};

__global__ __launch_bounds__(64) void geblnet_main(
    const float2* __restrict__ x2,      // (8192, 10, 9) complex
    const float2* __restrict__ w1g,     // (12,13,13) complex
    const float* __restrict__ dw,       // (24,)
    const float* __restrict__ db,       // (1,)
    const float4* __restrict__ CTt,     // (169,12)
    float* __restrict__ out)            // (8192,)
{
    __shared__ __align__(16) WeTU W;            // 1008 B
    __shared__ __align__(16) BsU  B;            // 6048 B
    __shared__ __align__(16) float2 Hs[12 * 10]; //  960 B (rows pad 10)
    // total 8016 B -> 8192 alloc

    const int t = threadIdx.x;
    const int p = blockIdx.x;

    // ---- phase 1: build We channels 0..12, TRANSPOSED WeT[ik][v]
    for (int j = t; j < 117; j += 64) {
        int v = j / 9, ik = j - v * 9;
        int i = ik / 3, jj = ik - i * 3;
        float2 val;
        if (v < 6) val = x2[(size_t)p * 90 + (4 + v) * 9 + ik];
        else if (v < 12) {
            float2 s = x2[(size_t)p * 90 + (v - 2) * 9 + jj * 3 + i];
            val = make_float2(s.x, -s.y);
        } else val = make_float2((i == jj) ? 1.f : 0.f, 0.f);
        W.weT[ik * 14 + v] = val;
    }
    __syncthreads();

    // ---- 2a preload: lane (rgrp 0..6, jk 0..8); We column -> registers ONCE
    const int rgrp = t / 9, jk = t - rgrp * 9;
    const bool alane = (rgrp < 7);
    float2 wc[13];
    if (alane) {
        #pragma unroll
        for (int w = 0; w < 13; ++w) wc[w] = W.weT[jk * 14 + w];
    }

    // ---- phase 2: layer 1, two u-half passes
    #pragma unroll 1
    for (int g = 0; g < 2; ++g) {
        const int u0 = g * 6;
        // 2a: B[uu][jk][v] = sum_w w1[u0+uu,v,w] * We[w][jk]
        //     Row sweep: 12 batches x 7 rows; w1 row from global (L1-hot),
        //     We column already in regs -> ZERO per-batch LDS reads.
        if (alane) {
            int row = rgrp;             // row = uu*13 + v, stride 7
            int uu = 0, v = rgrp;
            #pragma unroll 1
            for (int b = 0; b < 12; ++b) {
                int cu = uu, cv = v;
                if (row >= 78) { cu = 0; cv = 0; }   // clamp (write guarded)
                const float2* cp = w1g + ((u0 + cu) * 13 + cv) * 13;
                float br = 0.f, bi = 0.f;
                #pragma unroll
                for (int w = 0; w < 13; ++w) {
                    float2 cc = cp[w];
                    float2 ee = wc[w];
                    br += cc.x * ee.x - cc.y * ee.y;
                    bi += cc.x * ee.y + cc.y * ee.x;
                }
                if (row < 78)
                    B.bs[(cu * 9 + jk) * 14 + cv] = make_float2(br, bi);
                row += 7;
                v += 7;
                if (v >= 13) { v -= 13; ++uu; }
            }
        }
        __syncthreads();
        // 2b: H[u0+uu][i][k] = sum_{v,j} We[v][i][j] * B[uu][v][j*3+k]
        //     Both operands contiguous over v (16B-aligned rows -> b128).
        if (t < 54) {
            int uu = t / 9, ik = t - uu * 9;
            int i = ik / 3, k = ik - i * 3;
            float hr = 0.f, hi = 0.f;
            #pragma unroll
            for (int j = 0; j < 3; ++j) {
                const float2* wv = &W.weT[(i * 3 + j) * 14];
                const float2* bv = &B.bs[(uu * 9 + j * 3 + k) * 14];
                #pragma unroll
                for (int v = 0; v < 13; ++v) {
                    float2 a = wv[v], bb = bv[v];
                    hr += a.x * bb.x - a.y * bb.y;
                    hi += a.x * bb.y + a.y * bb.x;
                }
            }
            Hs[(u0 + uu) * 10 + ik] = make_float2(hr, hi);
        }
        __syncthreads();
    }

    // ---- phase 3: traces + gerelu + trnorm scales (WeT dead; overlay)
    {
        float2 tt = make_float2(0.f, 0.f);
        float gg = 0.f, tra_v = 0.f;
        if (t < 12) {
            float2 a = Hs[t * 10 + 0], b = Hs[t * 10 + 4], c = Hs[t * 10 + 8];
            tt = make_float2(a.x + b.x + c.x, a.y + b.y + c.y);
            gg = tt.x > 0.f ? tt.x : 0.f;
            tra_v = gg * sqrtf(tt.x * tt.x + tt.y * tt.y);
        }
        float m = tra_v;                 // lanes 12..15 contribute 0
        m += __shfl_xor(m, 1, 16);
        m += __shfl_xor(m, 2, 16);
        m += __shfl_xor(m, 4, 16);
        m += __shfl_xor(m, 8, 16);
        if (t < 12) {
            W.s.tr1[t] = tt;
            W.s.sc1[t] = gg / fmaxf(m * (1.f / 12.f), THRESH);
        }
    }
    __syncthreads();

    // ---- phase 4: Gram values -> GV (overlays B.bs; dead now)
    for (int it = t; it < 169; it += 64) {
        float2 val;
        if (it < 156) {
            int q = it < 78 ? it : it - 78;
            float fs = sqrtf(625.0f - 8.0f * (float)q);   // exact at edges
            int a = (int)((25.0f - fs) * 0.5f);
            int b = q - (a * (25 - a)) / 2 + a;
            const float2* Ha = &Hs[a * 10];
            const float2* Hb = &Hs[b * 10];
            float s = W.s.sc1[a] * W.s.sc1[b];
            float vr = 0.f, vi = 0.f;
            if (it < 78) {                    // S = tr(Aa Ab)
                #pragma unroll
                for (int i = 0; i < 3; ++i)
                    #pragma unroll
                    for (int jj = 0; jj < 3; ++jj) {
                        float2 A = Ha[i * 3 + jj], Bb = Hb[jj * 3 + i];
                        vr += A.x * Bb.x - A.y * Bb.y;
                        vi += A.x * Bb.y + A.y * Bb.x;
                    }
            } else {                          // Hm = tr(Aa Ab^H)
                #pragma unroll
                for (int e = 0; e < 9; ++e) {
                    float2 A = Ha[e], Bb = Hb[e];
                    vr += A.x * Bb.x + A.y * Bb.y;
                    vi += A.y * Bb.x - A.x * Bb.y;
                }
            }
            val = make_float2(s * vr, s * vi);
        } else if (it < 168) {
            int a = it - 156;
            float s = W.s.sc1[a]; float2 tt = W.s.tr1[a];
            val = make_float2(s * tt.x, s * tt.y);
        } else {
            val = make_float2(1.f, 0.f);
        }
        B.gv[it] = val;
    }
    __syncthreads();

    // ---- phase 5: coefficient contraction, lane=(q,u), 60 active
    if (t < 60) {
        int q = t / 12, u = t - q * 12;
        int i0 = q * 34, i1 = (q == 4) ? 169 : i0 + 34;
        float tre = 0.f, tim = 0.f;
        #pragma unroll 4
        for (int it = i0; it < i1; ++it) {
            float4 c = CTt[it * 12 + u];
            float2 gv = B.gv[it];
            tre += c.x * gv.x + c.y * gv.y;
            tim += c.z * gv.x + c.w * gv.y;
        }
        W.s.tpar[u * 5 + q] = make_float2(tre, tim);
    }
    __syncthreads();

    // ---- phase 6: layer-2 gerelu + trnorm + dense head (shuffle reduce)
    {
        float2 tt = make_float2(0.f, 0.f);
        float gg = 0.f, tra_v = 0.f;
        if (t < 12) {
            #pragma unroll
            for (int q = 0; q < 5; ++q) {
                float2 A = W.s.tpar[t * 5 + q];
                tt.x += A.x; tt.y += A.y;
            }
            gg = tt.x > 0.f ? tt.x : 0.f;
            tra_v = gg * sqrtf(tt.x * tt.x + tt.y * tt.y);
        }
        float m = tra_v;                 // lanes 12..15 contribute 0
        m += __shfl_xor(m, 1, 16);
        m += __shfl_xor(m, 2, 16);
        m += __shfl_xor(m, 4, 16);
        m += __shfl_xor(m, 8, 16);
        float term = 0.f;
        if (t < 12) {
            float inv = 1.f / fmaxf(m * (1.f / 12.f), THRESH);
            float s = gg * inv * (1.f / 3.f);
            term = s * (tt.x * dw[2 * t] + tt.y * dw[2 * t + 1]);
        }
        term += __shfl_xor(term, 1, 16);
        term += __shfl_xor(term, 2, 16);
        term += __shfl_xor(term, 4, 16);
        term += __shfl_xor(term, 8, 16);
        if (t == 0) out[p] = term + db[0];
    }
}

extern "C" void kernel_launch(void* const* d_in, const int* in_sizes, int n_in,
                              void* d_out, int out_size, void* d_ws, size_t ws_size,
                              hipStream_t stream) {
    const float* x  = (const float*)d_in[0];
    const float* w1 = (const float*)d_in[1];
    const float* w2 = (const float*)d_in[2];
    const float* dw = (const float*)d_in[3];
    const float* db = (const float*)d_in[4];
    float* outp = (float*)d_out;
    float4* CTt = (float4*)d_ws;          // 12*169*16 B = 32448 B

    geblnet_setup<<<(12 * 169 + 255) / 256, 256, 0, stream>>>(w2, CTt);

    geblnet_main<<<NPTS, 64, 0, stream>>>(
        (const float2*)x, (const float2*)w1, dw, db, CTt, outp);
}

// Round 7
// 121.824 us; speedup vs baseline: 1.0593x; 1.0593x over previous
//
#include <hip/hip_runtime.h>
#include <math.h>

// GEBLNet via Gram-matrix reduction.
// R24 = R19 base + v_pk_fma_f32 complex-MAC packing (+ coalesced P1).
// EVIDENCE LEDGER: falsified binders = VMEM count (R21), DS count (R23),
// occupancy/LDS/VGPR residency (R17-R20), point amortization (R22).
// Proven wins = conflict removal (R18, -4.7us), ILP unroll (R19, -8.8us).
// Remaining model: per-point floor = VALU issue + dependent FMA chains.
// This round halves both: each complex MAC = 2 x v_pk_fma_f32 (VOP3P
// op_sel/neg encodes the conj/swap structure; compiler never forms these
// from scalar code) in 2a/2b/P4/P5 -> wave FMA instrs ~1700 -> ~850.
//   - P1: ONE coalesced 432B load (x chans 4..9, 54 lanes), both We layouts
//     written from regs (old P1 loaded the same data twice, scattered).
//   - CTt re-laid in setup as (c0,c2,c1,c3) so P5 packed dot uses adjacent
//     float2 pairs.
//   - Layouts/LDS byte-identical to R19 (conflicts proven 98K).
// LESSON (R23): DS-count diet useless; avoid pad-14 layouts (conflicts).
// LESSON (R22): 2 pts/wave regresses. LESSON (R20): multi-wave wgs regress.
// LESSON (R19): unroll-2/4 ILP works; VGPR<=84 tolerable. LESSON (R18):
// broadcast LDS reads conflict-free. LESSON (R16): full 2a+2b merge
// regresses. LESSON (R15): fine-grained jobs. LESSON (R11): direct-w2
// regresses. LESSON (R4+R7): launch_bounds min-waves arg -> spill.
// LESSON (R6): unions / member-wise moves, no reinterpret-cast of locals.

#define NPTS 8192
#define THRESH 0.001f

typedef float f32x2 __attribute__((ext_vector_type(2)));

// acc += cc * ee (complex):  acc.lo += cc.lo*ee.lo - cc.hi*ee.hi
//                            acc.hi += cc.lo*ee.hi + cc.hi*ee.lo
static __device__ __forceinline__ void cmac(f32x2& acc, f32x2 cc, f32x2 ee) {
    asm("v_pk_fma_f32 %0, %1, %2, %0 op_sel:[0,0,0] op_sel_hi:[0,1,1]\n\t"
        "v_pk_fma_f32 %0, %1, %2, %0 op_sel:[1,1,0] op_sel_hi:[1,0,1] neg_lo:[1,0,0]"
        : "+v"(acc) : "v"(cc), "v"(ee));
}

// acc += A * conj(B):  acc.lo += A.lo*B.lo + A.hi*B.hi
//                      acc.hi += A.hi*B.lo - A.lo*B.hi
static __device__ __forceinline__ void cmacc(f32x2& acc, f32x2 A, f32x2 B) {
    asm("v_pk_fma_f32 %0, %1, %2, %0 op_sel:[0,0,0] op_sel_hi:[0,1,1] neg_hi:[1,0,0]\n\t"
        "v_pk_fma_f32 %0, %1, %2, %0 op_sel:[1,1,0] op_sel_hi:[1,0,1]"
        : "+v"(acc) : "v"(A), "v"(B));
}

// acc += (gv.lo * cA) + (gv.hi * cB)   [per-component]
static __device__ __forceinline__ void cdot(f32x2& acc, f32x2 gv, f32x2 cA, f32x2 cB) {
    asm("v_pk_fma_f32 %0, %1, %2, %0 op_sel:[0,0,0] op_sel_hi:[0,1,1]\n\t"
        "v_pk_fma_f32 %0, %1, %3, %0 op_sel:[1,0,0] op_sel_hi:[1,1,1]"
        : "+v"(acc) : "v"(gv), "v"(cA), "v"(cB));
}

static __device__ __forceinline__ f32x2 c2(float2 a) {
    f32x2 r; r.x = a.x; r.y = a.y; return r;
}

__global__ void geblnet_setup(const float* __restrict__ w2,
                              float4* __restrict__ CTt) {
    int j = blockIdx.x * blockDim.x + threadIdx.x;
    if (j >= 12 * 169) return;
    int u = j / 169, it = j % 169;
    const float* W = w2 + u * 25 * 25 * 2;
#define WR(v, w) W[((v) * 25 + (w)) * 2]
#define WI(v, w) W[((v) * 25 + (w)) * 2 + 1]
    float c0, c1, c2v, c3;
    if (it < 78) {                       // S pairs, a<=b
        int q = it, a = 0;
        while (q >= 12 - a) { q -= 12 - a; ++a; }
        int b = a + q;
        float ar = WR(a, b) + (a != b ? WR(b, a) : 0.f);
        float ai = WI(a, b) + (a != b ? WI(b, a) : 0.f);
        float br = WR(12 + a, 12 + b) + (a != b ? WR(12 + b, 12 + a) : 0.f);
        float bi = WI(12 + a, 12 + b) + (a != b ? WI(12 + b, 12 + a) : 0.f);
        c0 = ar + br; c1 = bi - ai; c2v = ai + bi; c3 = ar - br;
    } else if (it < 156) {               // Hm pairs, a<=b
        int q = it - 78, a = 0;
        while (q >= 12 - a) { q -= 12 - a; ++a; }
        int b = a + q;
        if (a != b) {
            float gr = WR(a, 12 + b) + WR(12 + b, a);
            float gi = WI(a, 12 + b) + WI(12 + b, a);
            float dr = WR(b, 12 + a) + WR(12 + a, b);
            float di = WI(b, 12 + a) + WI(12 + a, b);
            c0 = gr + dr; c1 = di - gi; c2v = gi + di; c3 = gr - dr;
        } else {
            float er = WR(a, 12 + a) + WR(12 + a, a);
            float ei = WI(a, 12 + a) + WI(12 + a, a);
            c0 = er; c1 = 0.f; c2v = ei; c3 = 0.f;
        }
    } else if (it < 168) {               // trace terms
        int a = it - 156;
        float fr = WR(a, 24) + WR(24, a), fi = WI(a, 24) + WI(24, a);
        float pr = WR(12 + a, 24) + WR(24, 12 + a);
        float pi = WI(12 + a, 24) + WI(24, 12 + a);
        c0 = fr + pr; c1 = pi - fi; c2v = fi + pi; c3 = fr - pr;
    } else {                             // unit-unit
        c0 = 3.f * WR(24, 24); c1 = 0.f; c2v = 3.f * WI(24, 24); c3 = 0.f;
    }
    // Packed layout for P5's cdot: pairs (c0,c2) and (c1,c3) adjacent.
    CTt[it * 12 + u] = make_float4(c0, c2v, c1, c3);
#undef WR
#undef WI
}

// Scratch union: bs dead after phase 2b; phase-3..6 scratch reuses it.
union Scr {
    float2 bs[702];                     // B[uu][v][jk], rows exact 9 (5616 B)
    struct {
        float2 tpar[60];                // phase 5 partials
        float2 tr1[12];                 // layer-1 traces (read in phase 4)
        float  sc1[12];                 // combined gerelu+trnorm scale
    } s;
};

__global__ __launch_bounds__(64) void geblnet_main(
    const float2* __restrict__ x2,      // (8192, 10, 9) complex
    const float2* __restrict__ w1g,     // (12,13,13) complex
    const float* __restrict__ dw,       // (24,)
    const float* __restrict__ db,       // (1,)
    const float4* __restrict__ CTt,     // (169,12) packed (c0,c2,c1,c3)
    float* __restrict__ out)            // (8192,)
{
    // Overlay: phases 1-2 = We row-major (13 ch incl. identity, stride 10);
    //          phases 4-5 = GV[169].
    __shared__ float2 WeGV[170];        // 1360 B
    __shared__ Scr S;                   // 5616 B
    __shared__ float2 Hs[108];          //  864 B
    // total 7840 B -> 8192 alloc

    const int t = threadIdx.x;
    const int p = blockIdx.x;

    // ---- phase 1: ONE coalesced read of x channels 4..9 (54 float2),
    //      write both We layouts (direct ch 0..5, conj-T ch 6..11) + identity.
    if (t < 54) {
        int xc = t / 9, ik = t - xc * 9;
        int i = ik / 3, j = ik - i * 3;
        float2 val = x2[(size_t)p * 90 + 36 + t];       // contiguous 432 B
        WeGV[xc * 10 + ik] = val;                        // direct
        WeGV[(6 + xc) * 10 + j * 3 + i] = make_float2(val.x, -val.y); // conj-T
    } else if (t < 63) {
        int ik = t - 54;
        WeGV[120 + ik] = make_float2((ik % 4 == 0) ? 1.f : 0.f, 0.f); // identity
    }
    __syncthreads();

    // ---- phase 2: layer 1 on all 64 lanes, two u-half passes
    #pragma unroll 1
    for (int g = 0; g < 2; ++g) {
        const int u0 = g * 6;
        // 2a: B[uu][v][jk] = sum_w w1[u0+uu,v,w] * We[w][jk]
        //     We read is per-w broadcast (addr depends only on jk): no
        //     bank conflicts. Incremental (uu,rem): e starts at t<117.
        {
            int uu = 0, rem = t;
            #pragma unroll 2
            for (int e = t; e < 702; e += 64) {
                int v = rem / 9, jk = rem - v * 9;
                const float2* cp = w1g + ((u0 + uu) * 13 + v) * 13; // contiguous
                f32x2 acc = {0.f, 0.f};
                #pragma unroll
                for (int w = 0; w < 13; ++w) {
                    cmac(acc, c2(cp[w]), c2(WeGV[w * 10 + jk]));
                }
                S.bs[(uu * 13 + v) * 9 + jk] = make_float2(acc.x, acc.y);
                rem += 64;
                if (rem >= 117) { rem -= 117; ++uu; }
            }
        }
        __syncthreads();
        // 2b: H[u0+uu][i][k] = sum_{v,j} We[v][i][j] * B[uu][v][j*3+k]
        if (t < 54) {
            int uu = t / 9, ik = t - uu * 9;
            int i = ik / 3, k = ik - i * 3;
            f32x2 h = {0.f, 0.f};
            #pragma unroll
            for (int v = 0; v < 13; ++v) {
                const float2* a = &WeGV[v * 10 + i * 3];
                const float2* b = &S.bs[(uu * 13 + v) * 9 + k];
                #pragma unroll
                for (int j = 0; j < 3; ++j) {
                    cmac(h, c2(a[j]), c2(b[j * 3]));
                }
            }
            Hs[(u0 + uu) * 9 + ik] = make_float2(h.x, h.y);
        }
        __syncthreads();
    }

    // ---- phase 3: traces + gerelu + trnorm scales (shuffle reduce, 1 barrier)
    {
        float2 tt = make_float2(0.f, 0.f);
        float gg = 0.f, tra_v = 0.f;
        if (t < 12) {
            float2 a = Hs[t * 9 + 0], b = Hs[t * 9 + 4], c = Hs[t * 9 + 8];
            tt = make_float2(a.x + b.x + c.x, a.y + b.y + c.y);
            gg = tt.x > 0.f ? tt.x : 0.f;
            tra_v = gg * sqrtf(tt.x * tt.x + tt.y * tt.y);
        }
        float m = tra_v;                 // lanes 12..15 contribute 0
        m += __shfl_xor(m, 1, 16);
        m += __shfl_xor(m, 2, 16);
        m += __shfl_xor(m, 4, 16);
        m += __shfl_xor(m, 8, 16);
        if (t < 12) {
            S.s.tr1[t] = tt;
            S.s.sc1[t] = gg / fmaxf(m * (1.f / 12.f), THRESH);
        }
    }
    __syncthreads();

    // ---- phase 4: Gram values -> GV (overlays We row-major; dead now)
    for (int it = t; it < 169; it += 64) {
        float2 val;
        if (it < 156) {
            int q = it < 78 ? it : it - 78;
            float fs = sqrtf(625.0f - 8.0f * (float)q);   // exact at bucket edges
            int a = (int)((25.0f - fs) * 0.5f);
            int b = q - (a * (25 - a)) / 2 + a;
            const float2* Ha = &Hs[a * 9];
            const float2* Hb = &Hs[b * 9];
            float s = S.s.sc1[a] * S.s.sc1[b];
            f32x2 vv = {0.f, 0.f};
            if (it < 78) {                    // S = tr(Aa Ab)
                #pragma unroll
                for (int i = 0; i < 3; ++i)
                    #pragma unroll
                    for (int jj = 0; jj < 3; ++jj)
                        cmac(vv, c2(Ha[i * 3 + jj]), c2(Hb[jj * 3 + i]));
            } else {                          // Hm = tr(Aa Ab^H)
                #pragma unroll
                for (int e = 0; e < 9; ++e)
                    cmacc(vv, c2(Ha[e]), c2(Hb[e]));
            }
            val = make_float2(s * vv.x, s * vv.y);
        } else if (it < 168) {
            int a = it - 156;
            float s = S.s.sc1[a]; float2 tt = S.s.tr1[a];
            val = make_float2(s * tt.x, s * tt.y);
        } else {
            val = make_float2(1.f, 0.f);
        }
        WeGV[it] = val;
    }
    __syncthreads();

    // ---- phase 5: coefficient contraction, lane=(q,u), 60 active
    if (t < 60) {
        int q = t / 12, u = t - q * 12;
        int i0 = q * 34, i1 = (q == 4) ? 169 : i0 + 34;
        f32x2 acc = {0.f, 0.f};
        #pragma unroll 4
        for (int it = i0; it < i1; ++it) {
            float4 c = CTt[it * 12 + u];          // (c0,c2,c1,c3)
            f32x2 cA; cA.x = c.x; cA.y = c.y;
            f32x2 cB; cB.x = c.z; cB.y = c.w;
            cdot(acc, c2(WeGV[it]), cA, cB);
        }
        S.s.tpar[u * 5 + q] = make_float2(acc.x, acc.y);
    }
    __syncthreads();

    // ---- phase 6: layer-2 gerelu + trnorm + dense head (shuffle, 0 barrier)
    {
        float2 tt = make_float2(0.f, 0.f);
        float gg = 0.f, tra_v = 0.f;
        if (t < 12) {
            #pragma unroll
            for (int q = 0; q < 5; ++q) {
                float2 A = S.s.tpar[t * 5 + q];
                tt.x += A.x; tt.y += A.y;
            }
            gg = tt.x > 0.f ? tt.x : 0.f;
            tra_v = gg * sqrtf(tt.x * tt.x + tt.y * tt.y);
        }
        float m = tra_v;                 // lanes 12..15 contribute 0
        m += __shfl_xor(m, 1, 16);
        m += __shfl_xor(m, 2, 16);
        m += __shfl_xor(m, 4, 16);
        m += __shfl_xor(m, 8, 16);
        float term = 0.f;
        if (t < 12) {
            float inv = 1.f / fmaxf(m * (1.f / 12.f), THRESH);
            float s = gg * inv * (1.f / 3.f);
            term = s * (tt.x * dw[2 * t] + tt.y * dw[2 * t + 1]);
        }
        term += __shfl_xor(term, 1, 16);
        term += __shfl_xor(term, 2, 16);
        term += __shfl_xor(term, 4, 16);
        term += __shfl_xor(term, 8, 16);
        if (t == 0) out[p] = term + db[0];
    }
}

extern "C" void kernel_launch(void* const* d_in, const int* in_sizes, int n_in,
                              void* d_out, int out_size, void* d_ws, size_t ws_size,
                              hipStream_t stream) {
    const float* x  = (const float*)d_in[0];
    const float* w1 = (const float*)d_in[1];
    const float* w2 = (const float*)d_in[2];
    const float* dw = (const float*)d_in[3];
    const float* db = (const float*)d_in[4];
    float* outp = (float*)d_out;
    float4* CTt = (float4*)d_ws;          // 12*169*16 B = 32448 B

    geblnet_setup<<<(12 * 169 + 255) / 256, 256, 0, stream>>>(w2, CTt);

    geblnet_main<<<NPTS, 64, 0, stream>>>(
        (const float2*)x, (const float2*)w1, dw, db, CTt, outp);
}

// Round 8
// 116.771 us; speedup vs baseline: 1.1051x; 1.0433x over previous
//
#include <hip/hip_runtime.h>
#include <math.h>

// GEBLNet via Gram-matrix reduction.
// R25 = R24 + accumulator CHAIN-SPLITTING (ILP on dependent pk-fma chains).
// EVIDENCE: R24 halved VALU issue (VALUBusy 56->36, dur -4.3us) -> no pipe
// >40% busy now; per-wave life ~60k cy vs ~3k issue cy at 3 waves/SIMD ->
// dependent-chain latency is the remaining exposed cost. R24's packing made
// chains SERIAL (2a 26/job, 2b 156, P5 68 deep). This round splits them:
//   2a: even/odd-w accs (4 chains in flight with unroll-2),
//   2b: 3 accs by j (chain 52),
//   P4: 2-way by element parity,
//   P5: manual 4x unroll, 4 NAMED accs (rule: no runtime-indexed arrays).
// LEDGER: falsified binders = VMEM count (R21), DS count (R23), occupancy/
// LDS/VGPR residency (R17-R20), point amortization (R22), VALU issue alone
// (R24 partial). Proven wins = conflict removal (R18), load-ILP (R19),
// pk-fma packing (R24). LESSON (R23): avoid pad-14 layouts. LESSON (R22):
// 2 pts/wave regresses. LESSON (R20): multi-wave wgs regress. LESSON (R16):
// full 2a+2b merge regresses. LESSON (R4+R7): launch_bounds min-waves arg
// -> spill. LESSON (R6): unions, no reinterpret-cast of locals.

#define NPTS 8192
#define THRESH 0.001f

typedef float f32x2 __attribute__((ext_vector_type(2)));

// acc += cc * ee (complex)
static __device__ __forceinline__ void cmac(f32x2& acc, f32x2 cc, f32x2 ee) {
    asm("v_pk_fma_f32 %0, %1, %2, %0 op_sel:[0,0,0] op_sel_hi:[0,1,1]\n\t"
        "v_pk_fma_f32 %0, %1, %2, %0 op_sel:[1,1,0] op_sel_hi:[1,0,1] neg_lo:[1,0,0]"
        : "+v"(acc) : "v"(cc), "v"(ee));
}

// acc += A * conj(B)
static __device__ __forceinline__ void cmacc(f32x2& acc, f32x2 A, f32x2 B) {
    asm("v_pk_fma_f32 %0, %1, %2, %0 op_sel:[0,0,0] op_sel_hi:[0,1,1] neg_hi:[1,0,0]\n\t"
        "v_pk_fma_f32 %0, %1, %2, %0 op_sel:[1,1,0] op_sel_hi:[1,0,1]"
        : "+v"(acc) : "v"(A), "v"(B));
}

// acc += (gv.lo * cA) + (gv.hi * cB)   [per-component]
static __device__ __forceinline__ void cdot(f32x2& acc, f32x2 gv, f32x2 cA, f32x2 cB) {
    asm("v_pk_fma_f32 %0, %1, %2, %0 op_sel:[0,0,0] op_sel_hi:[0,1,1]\n\t"
        "v_pk_fma_f32 %0, %1, %3, %0 op_sel:[1,0,0] op_sel_hi:[1,1,1]"
        : "+v"(acc) : "v"(gv), "v"(cA), "v"(cB));
}

static __device__ __forceinline__ f32x2 c2(float2 a) {
    f32x2 r; r.x = a.x; r.y = a.y; return r;
}

__global__ void geblnet_setup(const float* __restrict__ w2,
                              float4* __restrict__ CTt) {
    int j = blockIdx.x * blockDim.x + threadIdx.x;
    if (j >= 12 * 169) return;
    int u = j / 169, it = j % 169;
    const float* W = w2 + u * 25 * 25 * 2;
#define WR(v, w) W[((v) * 25 + (w)) * 2]
#define WI(v, w) W[((v) * 25 + (w)) * 2 + 1]
    float c0, c1, c2v, c3;
    if (it < 78) {                       // S pairs, a<=b
        int q = it, a = 0;
        while (q >= 12 - a) { q -= 12 - a; ++a; }
        int b = a + q;
        float ar = WR(a, b) + (a != b ? WR(b, a) : 0.f);
        float ai = WI(a, b) + (a != b ? WI(b, a) : 0.f);
        float br = WR(12 + a, 12 + b) + (a != b ? WR(12 + b, 12 + a) : 0.f);
        float bi = WI(12 + a, 12 + b) + (a != b ? WI(12 + b, 12 + a) : 0.f);
        c0 = ar + br; c1 = bi - ai; c2v = ai + bi; c3 = ar - br;
    } else if (it < 156) {               // Hm pairs, a<=b
        int q = it - 78, a = 0;
        while (q >= 12 - a) { q -= 12 - a; ++a; }
        int b = a + q;
        if (a != b) {
            float gr = WR(a, 12 + b) + WR(12 + b, a);
            float gi = WI(a, 12 + b) + WI(12 + b, a);
            float dr = WR(b, 12 + a) + WR(12 + a, b);
            float di = WI(b, 12 + a) + WI(12 + a, b);
            c0 = gr + dr; c1 = di - gi; c2v = gi + di; c3 = gr - dr;
        } else {
            float er = WR(a, 12 + a) + WR(12 + a, a);
            float ei = WI(a, 12 + a) + WI(12 + a, a);
            c0 = er; c1 = 0.f; c2v = ei; c3 = 0.f;
        }
    } else if (it < 168) {               // trace terms
        int a = it - 156;
        float fr = WR(a, 24) + WR(24, a), fi = WI(a, 24) + WI(24, a);
        float pr = WR(12 + a, 24) + WR(24, 12 + a);
        float pi = WI(12 + a, 24) + WI(24, 12 + a);
        c0 = fr + pr; c1 = pi - fi; c2v = fi + pi; c3 = fr - pr;
    } else {                             // unit-unit
        c0 = 3.f * WR(24, 24); c1 = 0.f; c2v = 3.f * WI(24, 24); c3 = 0.f;
    }
    // Packed layout for P5's cdot: pairs (c0,c2) and (c1,c3) adjacent.
    CTt[it * 12 + u] = make_float4(c0, c2v, c1, c3);
#undef WR
#undef WI
}

// Scratch union: bs dead after phase 2b; phase-3..6 scratch reuses it.
union Scr {
    float2 bs[702];                     // B[uu][v][jk], rows exact 9 (5616 B)
    struct {
        float2 tpar[60];                // phase 5 partials
        float2 tr1[12];                 // layer-1 traces (read in phase 4)
        float  sc1[12];                 // combined gerelu+trnorm scale
    } s;
};

__global__ __launch_bounds__(64) void geblnet_main(
    const float2* __restrict__ x2,      // (8192, 10, 9) complex
    const float2* __restrict__ w1g,     // (12,13,13) complex
    const float* __restrict__ dw,       // (24,)
    const float* __restrict__ db,       // (1,)
    const float4* __restrict__ CTt,     // (169,12) packed (c0,c2,c1,c3)
    float* __restrict__ out)            // (8192,)
{
    // Overlay: phases 1-2 = We row-major (13 ch incl. identity, stride 10);
    //          phases 4-5 = GV[169].
    __shared__ float2 WeGV[170];        // 1360 B
    __shared__ Scr S;                   // 5616 B
    __shared__ float2 Hs[108];          //  864 B
    // total 7840 B -> 8192 alloc

    const int t = threadIdx.x;
    const int p = blockIdx.x;

    // ---- phase 1: ONE coalesced read of x channels 4..9 (54 float2),
    //      write both We layouts (direct ch 0..5, conj-T ch 6..11) + identity.
    if (t < 54) {
        int xc = t / 9, ik = t - xc * 9;
        int i = ik / 3, j = ik - i * 3;
        float2 val = x2[(size_t)p * 90 + 36 + t];       // contiguous 432 B
        WeGV[xc * 10 + ik] = val;                        // direct
        WeGV[(6 + xc) * 10 + j * 3 + i] = make_float2(val.x, -val.y); // conj-T
    } else if (t < 63) {
        int ik = t - 54;
        WeGV[120 + ik] = make_float2((ik % 4 == 0) ? 1.f : 0.f, 0.f); // identity
    }
    __syncthreads();

    // ---- phase 2: layer 1 on all 64 lanes, two u-half passes
    #pragma unroll 1
    for (int g = 0; g < 2; ++g) {
        const int u0 = g * 6;
        // 2a: B[uu][v][jk] = sum_w w1[u0+uu,v,w] * We[w][jk]
        //     Even/odd-w split accs: 2 chains/job x unroll-2 = 4 in flight.
        {
            int uu = 0, rem = t;
            #pragma unroll 2
            for (int e = t; e < 702; e += 64) {
                int v = rem / 9, jk = rem - v * 9;
                const float2* cp = w1g + ((u0 + uu) * 13 + v) * 13; // contiguous
                f32x2 a0 = {0.f, 0.f}, a1 = {0.f, 0.f};
                #pragma unroll
                for (int w = 0; w < 12; w += 2) {
                    cmac(a0, c2(cp[w]),     c2(WeGV[w * 10 + jk]));
                    cmac(a1, c2(cp[w + 1]), c2(WeGV[(w + 1) * 10 + jk]));
                }
                cmac(a0, c2(cp[12]), c2(WeGV[120 + jk]));
                S.bs[(uu * 13 + v) * 9 + jk] =
                    make_float2(a0.x + a1.x, a0.y + a1.y);
                rem += 64;
                if (rem >= 117) { rem -= 117; ++uu; }
            }
        }
        __syncthreads();
        // 2b: H[u0+uu][i][k] = sum_{v,j} We[v][i][j] * B[uu][v][j*3+k]
        //     3 accs by j: chain 156 -> 52.
        if (t < 54) {
            int uu = t / 9, ik = t - uu * 9;
            int i = ik / 3, k = ik - i * 3;
            f32x2 h0 = {0.f, 0.f}, h1 = {0.f, 0.f}, h2 = {0.f, 0.f};
            #pragma unroll
            for (int v = 0; v < 13; ++v) {
                const float2* a = &WeGV[v * 10 + i * 3];
                const float2* b = &S.bs[(uu * 13 + v) * 9 + k];
                cmac(h0, c2(a[0]), c2(b[0]));
                cmac(h1, c2(a[1]), c2(b[3]));
                cmac(h2, c2(a[2]), c2(b[6]));
            }
            Hs[(u0 + uu) * 9 + ik] =
                make_float2(h0.x + h1.x + h2.x, h0.y + h1.y + h2.y);
        }
        __syncthreads();
    }

    // ---- phase 3: traces + gerelu + trnorm scales (shuffle reduce, 1 barrier)
    {
        float2 tt = make_float2(0.f, 0.f);
        float gg = 0.f, tra_v = 0.f;
        if (t < 12) {
            float2 a = Hs[t * 9 + 0], b = Hs[t * 9 + 4], c = Hs[t * 9 + 8];
            tt = make_float2(a.x + b.x + c.x, a.y + b.y + c.y);
            gg = tt.x > 0.f ? tt.x : 0.f;
            tra_v = gg * sqrtf(tt.x * tt.x + tt.y * tt.y);
        }
        float m = tra_v;                 // lanes 12..15 contribute 0
        m += __shfl_xor(m, 1, 16);
        m += __shfl_xor(m, 2, 16);
        m += __shfl_xor(m, 4, 16);
        m += __shfl_xor(m, 8, 16);
        if (t < 12) {
            S.s.tr1[t] = tt;
            S.s.sc1[t] = gg / fmaxf(m * (1.f / 12.f), THRESH);
        }
    }
    __syncthreads();

    // ---- phase 4: Gram values -> GV (overlays We row-major; dead now)
    //      2-way split accs by element parity.
    for (int it = t; it < 169; it += 64) {
        float2 val;
        if (it < 156) {
            int q = it < 78 ? it : it - 78;
            float fs = sqrtf(625.0f - 8.0f * (float)q);   // exact at bucket edges
            int a = (int)((25.0f - fs) * 0.5f);
            int b = q - (a * (25 - a)) / 2 + a;
            const float2* Ha = &Hs[a * 9];
            const float2* Hb = &Hs[b * 9];
            float s = S.s.sc1[a] * S.s.sc1[b];
            f32x2 v0 = {0.f, 0.f}, v1 = {0.f, 0.f};
            if (it < 78) {                    // S = tr(Aa Ab)
                #pragma unroll
                for (int i = 0; i < 3; ++i)
                    #pragma unroll
                    for (int jj = 0; jj < 3; ++jj) {
                        if (((i * 3 + jj) & 1) == 0)
                            cmac(v0, c2(Ha[i * 3 + jj]), c2(Hb[jj * 3 + i]));
                        else
                            cmac(v1, c2(Ha[i * 3 + jj]), c2(Hb[jj * 3 + i]));
                    }
            } else {                          // Hm = tr(Aa Ab^H)
                #pragma unroll
                for (int e = 0; e < 9; ++e) {
                    if ((e & 1) == 0) cmacc(v0, c2(Ha[e]), c2(Hb[e]));
                    else              cmacc(v1, c2(Ha[e]), c2(Hb[e]));
                }
            }
            val = make_float2(s * (v0.x + v1.x), s * (v0.y + v1.y));
        } else if (it < 168) {
            int a = it - 156;
            float s = S.s.sc1[a]; float2 tt = S.s.tr1[a];
            val = make_float2(s * tt.x, s * tt.y);
        } else {
            val = make_float2(1.f, 0.f);
        }
        WeGV[it] = val;
    }
    __syncthreads();

    // ---- phase 5: coefficient contraction, lane=(q,u), 60 active
    //      Manual 4x unroll, 4 NAMED accumulators (chain 68 -> 17).
    if (t < 60) {
        int q = t / 12, u = t - q * 12;
        int i0 = q * 34, i1 = (q == 4) ? 169 : i0 + 34;
        f32x2 A0 = {0.f, 0.f}, A1 = {0.f, 0.f};
        f32x2 A2 = {0.f, 0.f}, A3 = {0.f, 0.f};
        int it = i0;
        #pragma unroll 1
        for (; it + 4 <= i1; it += 4) {
            float4 c0v = CTt[(it + 0) * 12 + u];
            float4 c1v = CTt[(it + 1) * 12 + u];
            float4 c2c = CTt[(it + 2) * 12 + u];
            float4 c3v = CTt[(it + 3) * 12 + u];
            float2 g0 = WeGV[it + 0], g1 = WeGV[it + 1];
            float2 g2 = WeGV[it + 2], g3 = WeGV[it + 3];
            f32x2 cA, cB;
            cA.x = c0v.x; cA.y = c0v.y; cB.x = c0v.z; cB.y = c0v.w;
            cdot(A0, c2(g0), cA, cB);
            cA.x = c1v.x; cA.y = c1v.y; cB.x = c1v.z; cB.y = c1v.w;
            cdot(A1, c2(g1), cA, cB);
            cA.x = c2c.x; cA.y = c2c.y; cB.x = c2c.z; cB.y = c2c.w;
            cdot(A2, c2(g2), cA, cB);
            cA.x = c3v.x; cA.y = c3v.y; cB.x = c3v.z; cB.y = c3v.w;
            cdot(A3, c2(g3), cA, cB);
        }
        for (; it < i1; ++it) {
            float4 c = CTt[it * 12 + u];
            f32x2 cA, cB;
            cA.x = c.x; cA.y = c.y; cB.x = c.z; cB.y = c.w;
            cdot(A0, c2(WeGV[it]), cA, cB);
        }
        S.s.tpar[u * 5 + q] =
            make_float2(A0.x + A1.x + A2.x + A3.x,
                        A0.y + A1.y + A2.y + A3.y);
    }
    __syncthreads();

    // ---- phase 6: layer-2 gerelu + trnorm + dense head (shuffle, 0 barrier)
    {
        float2 tt = make_float2(0.f, 0.f);
        float gg = 0.f, tra_v = 0.f;
        if (t < 12) {
            #pragma unroll
            for (int q = 0; q < 5; ++q) {
                float2 A = S.s.tpar[t * 5 + q];
                tt.x += A.x; tt.y += A.y;
            }
            gg = tt.x > 0.f ? tt.x : 0.f;
            tra_v = gg * sqrtf(tt.x * tt.x + tt.y * tt.y);
        }
        float m = tra_v;                 // lanes 12..15 contribute 0
        m += __shfl_xor(m, 1, 16);
        m += __shfl_xor(m, 2, 16);
        m += __shfl_xor(m, 4, 16);
        m += __shfl_xor(m, 8, 16);
        float term = 0.f;
        if (t < 12) {
            float inv = 1.f / fmaxf(m * (1.f / 12.f), THRESH);
            float s = gg * inv * (1.f / 3.f);
            term = s * (tt.x * dw[2 * t] + tt.y * dw[2 * t + 1]);
        }
        term += __shfl_xor(term, 1, 16);
        term += __shfl_xor(term, 2, 16);
        term += __shfl_xor(term, 4, 16);
        term += __shfl_xor(term, 8, 16);
        if (t == 0) out[p] = term + db[0];
    }
}

extern "C" void kernel_launch(void* const* d_in, const int* in_sizes, int n_in,
                              void* d_out, int out_size, void* d_ws, size_t ws_size,
                              hipStream_t stream) {
    const float* x  = (const float*)d_in[0];
    const float* w1 = (const float*)d_in[1];
    const float* w2 = (const float*)d_in[2];
    const float* dw = (const float*)d_in[3];
    const float* db = (const float*)d_in[4];
    float* outp = (float*)d_out;
    float4* CTt = (float4*)d_ws;          // 12*169*16 B = 32448 B

    geblnet_setup<<<(12 * 169 + 255) / 256, 256, 0, stream>>>(w2, CTt);

    geblnet_main<<<NPTS, 64, 0, stream>>>(
        (const float2*)x, (const float2*)w1, dw, db, CTt, outp);
}